// Round 22
// baseline (283.703 us; speedup 1.0000x reference)
//
#include <hip/hip_runtime.h>
#include <hip/hip_fp16.h>
#include <math.h>

#define NNODES 50000
#define NEDGES 800000
#define DIN    256
#define DHID   128
#define NCLS   40

#define BW    128                    // dst values per bucket
#define NBK   391                    // ceil(NNODES / BW)
#define CAP   6144                   // LDS col capacity per bucket (mean 2048, sd ~45)
#define PPART 256                    // partition blocks per view
#define CHUNK 3128                   // per-block edge span (mult of 4 -> int4 aligned)
#define CPAD  64                     // col array tail padding (zeroed)
#define BK    32                     // fc1 k-tile
#define MT    32                     // fc1 node tile (grid 1563 -> ~6 blocks/CU)

typedef _Float16 h2v __attribute__((ext_vector_type(2)));
union HF8 { float4 f; __half2 h2[4]; h2v v[4]; };   // 8 fp16 <-> 16 B
union HF4 { float2 f; __half2 h2[2]; };             // 4 fp16 <-> 8 B

// single-cycle cross-lane add via DPP (ctrl must be a compile-time constant)
template <int CTRL>
__device__ __forceinline__ float dpp_add(float d) {
  int t = __builtin_amdgcn_update_dpp(0, __float_as_int(d), CTRL, 0xf, 0xf, true);
  return d + __int_as_float(t);
}
// sum over each 16-lane row; all 16 lanes receive the identical total.
__device__ __forceinline__ float rowsum16(float d) {
  d = dpp_add<0xB1>(d);    // quad_perm [1,0,3,2]  (xor 1)
  d = dpp_add<0x4E>(d);    // quad_perm [2,3,0,1]  (xor 2)
  d = dpp_add<0x141>(d);   // row_half_mirror      (xor 7 pairing of quad sums)
  d = dpp_add<0x128>(d);   // row_ror:8            (xor 8 across 16-row halves)
  return d;
}

// ---------------- fc1: register-blocked GEMM + fused relu/fp16/row-norm ------
// 32 nodes x 128 cols per 256-thread block (grid 1563 -> ~6 blocks/CU, fixes
// the 3-blocks/CU grid starvation seen at 64-node tiles). Thread = 2m x 8n.
// Same k-ascending accumulation order per output -> bit-exact vs 64-node tile.
__global__ __launch_bounds__(256) void fc1_kernel(
    const float* __restrict__ X, const float* __restrict__ W1,
    const float* __restrict__ b1, __half* __restrict__ x1h,
    float* __restrict__ inv1)
{
  __shared__ float As[BK][33];       // X^T tile [k][m], padded (4.2 KB)
  __shared__ float Bs[BK][132];      // W1 tile [k][n], padded (16.9 KB)
  const int tid   = threadIdx.x;
  const int node0 = blockIdx.x * MT;
  const int tx    = tid & 15;        // n-groups: cols {tx*4..+3} u {64+tx*4..+3}
  const int ty    = tid >> 4;        // 0..15 -> rows ty*2, ty*2+1

  float acc[2][8];
#pragma unroll
  for (int i = 0; i < 2; ++i)
#pragma unroll
    for (int j = 0; j < 8; ++j) acc[i][j] = 0.f;

  for (int kt = 0; kt < DIN / BK; ++kt) {
    const int k0 = kt * BK;
    // stage A (X^T): 1 float4 per thread, scalar transpose into As[k][m]
    {
      const int row  = tid >> 3;           // 0..31
      const int kk   = (tid & 7) * 4;      // 0..28
      const int mrow = (node0 + row < NNODES) ? node0 + row : NNODES - 1;
      const float4 v = *(const float4*)(X + (size_t)mrow * DIN + k0 + kk);
      As[kk + 0][row] = v.x; As[kk + 1][row] = v.y;
      As[kk + 2][row] = v.z; As[kk + 3][row] = v.w;
    }
    // stage B (W1): 4 float4 per thread, coalesced
#pragma unroll
    for (int q = 0; q < 4; ++q) {
      const int flat = q * 256 + tid;      // float4 index in BKx32 grid
      const int kk   = flat >> 5;          // 0..31
      const int nn   = (flat & 31) * 4;    // 0..124
      *(float4*)&Bs[kk][nn] = *(const float4*)(W1 + (size_t)(k0 + kk) * DHID + nn);
    }
    __syncthreads();

#pragma unroll 4
    for (int k = 0; k < BK; ++k) {
      const float2 a  = *(const float2*)&As[k][ty * 2];
      const float4 b0 = *(const float4*)&Bs[k][tx * 4];
      const float4 b1v= *(const float4*)&Bs[k][64 + tx * 4];
      const float av[2] = {a.x, a.y};
      const float bv[8] = {b0.x, b0.y, b0.z, b0.w, b1v.x, b1v.y, b1v.z, b1v.w};
#pragma unroll
      for (int i = 0; i < 2; ++i)
#pragma unroll
        for (int j = 0; j < 8; ++j) acc[i][j] += av[i] * bv[j];
    }
    __syncthreads();
  }

  const float4 bb0 = *(const float4*)(b1 + tx * 4);
  const float4 bb1 = *(const float4*)(b1 + 64 + tx * 4);
  const float bias[8] = {bb0.x, bb0.y, bb0.z, bb0.w, bb1.x, bb1.y, bb1.z, bb1.w};

#pragma unroll
  for (int i = 0; i < 2; ++i) {
    const int row = node0 + ty * 2 + i;
    float v[8];
    float q = 0.f;
#pragma unroll
    for (int j = 0; j < 8; ++j) {
      float t = acc[i][j] + bias[j];
      t = t > 0.f ? t : 0.f;
      v[j] = t;
      q += t * t;
    }
    q = rowsum16(q);                 // reduce over the 16 tx lanes (DPP)
    if (row < NNODES) {
      HF4 o0, o1;
      o0.h2[0] = __floats2half2_rn(v[0], v[1]);
      o0.h2[1] = __floats2half2_rn(v[2], v[3]);
      o1.h2[0] = __floats2half2_rn(v[4], v[5]);
      o1.h2[1] = __floats2half2_rn(v[6], v[7]);
      *(float2*)(x1h + (size_t)row * DHID + tx * 4)      = o0.f;
      *(float2*)(x1h + (size_t)row * DHID + 64 + tx * 4) = o1.f;
      if (tx == 0) inv1[row] = 1.0f / fmaxf(sqrtf(q), 1e-12f);
    }
  }
}

// ---------------- fc2: out = x3h @ W2 + b2, 8 nodes/block (320 thr) ----------
__global__ __launch_bounds__(320) void fc2_kernel(
    const __half* __restrict__ x3h, const float* __restrict__ W2,
    const float* __restrict__ b2, float* __restrict__ out)
{
  __shared__ float Xs[8][DHID];      // 4 KB
  const int tid   = threadIdx.x;
  const int node0 = blockIdx.x * 8;
  if (tid < 128) {                   // 8 rows x 128 halves = 128 x 16B chunks
    HF8 u; u.f = *(const float4*)(x3h + (size_t)node0 * DHID + tid * 8);
    float* dst = &Xs[0][0] + tid * 8;
#pragma unroll
    for (int i = 0; i < 4; ++i) {
      const float2 t = __half22float2(u.h2[i]);
      dst[2 * i] = t.x; dst[2 * i + 1] = t.y;
    }
  }
  __syncthreads();

  const int ns = tid / NCLS;         // 0..7
  const int c  = tid - ns * NCLS;    // 0..39
  float acc = b2[c];
#pragma unroll 8
  for (int k = 0; k < DHID; ++k) acc += Xs[ns][k] * W2[k * NCLS + c];
  out[(size_t)(node0 + ns) * NCLS + c] = acc;
}

// ---------------- CSR build: deterministic two-pass multi-split --------------
__global__ __launch_bounds__(256) void hist_part_kernel(
    const int* __restrict__ dst1, const int* __restrict__ dst2,
    int* __restrict__ H)
{
  const int bid = blockIdx.x;
  const int v   = bid >= PPART;
  const int p   = v ? bid - PPART : bid;
  const int* __restrict__ dst = v ? dst2 : dst1;

  __shared__ int hist[NBK];
  for (int i = threadIdx.x; i < NBK; i += 256) hist[i] = 0;
  __syncthreads();
  const int beg = p * CHUNK;
  const int end = (beg + CHUNK < NEDGES) ? beg + CHUNK : NEDGES;
  const int nfull = (end - beg) & ~3;
  for (int j = beg + threadIdx.x * 4; j < beg + nfull; j += 1024) {
    const int4 d4 = *(const int4*)(dst + j);
    atomicAdd(&hist[d4.x >> 7], 1);
    atomicAdd(&hist[d4.y >> 7], 1);
    atomicAdd(&hist[d4.z >> 7], 1);
    atomicAdd(&hist[d4.w >> 7], 1);
  }
  for (int j = beg + nfull + threadIdx.x; j < end; j += 256)
    atomicAdd(&hist[dst[j] >> 7], 1);
  __syncthreads();
  for (int i = threadIdx.x; i < NBK; i += 256)
    H[(v * NBK + i) * PPART + p] = hist[i];
}

__global__ __launch_bounds__(PPART) void scan_bucket_kernel(
    int* __restrict__ H, int* __restrict__ btot)
{
  const int b   = blockIdx.x;        // 0..2*NBK-1
  const int tid = threadIdx.x;
  __shared__ int sm[PPART];
  const int v = H[b * PPART + tid];
  sm[tid] = v;
  __syncthreads();
  for (int off = 1; off < PPART; off <<= 1) {
    int t = (tid >= off) ? sm[tid - off] : 0;
    __syncthreads();
    sm[tid] += t;
    __syncthreads();
  }
  H[b * PPART + tid] = sm[tid] - v;  // exclusive within bucket
  if (tid == PPART - 1) btot[b] = sm[tid];
}

__global__ __launch_bounds__(1024) void scan_btot_kernel(
    const int* __restrict__ btot, int* __restrict__ boffG,
    int* __restrict__ col1, int* __restrict__ col2)
{
  __shared__ int sm[1024];
  const int tid = threadIdx.x;
  // zero the col tail pads (agnn prefetches read past segment ends)
  if (tid >= 768 && tid < 768 + CPAD) col1[NEDGES + tid - 768] = 0;
  if (tid >= 832 && tid < 832 + CPAD) col2[NEDGES + tid - 832] = 0;
  const int v = (tid < 2 * NBK) ? btot[tid] : 0;
  sm[tid] = v;
  __syncthreads();
  for (int off = 1; off < 1024; off <<= 1) {
    int t = (tid >= off) ? sm[tid - off] : 0;
    __syncthreads();
    sm[tid] += t;
    __syncthreads();
  }
  if (tid < 2 * NBK) boffG[tid] = sm[tid] - v;
  if (tid == 0) boffG[2 * NBK] = 2 * NEDGES;
}

// st element: (dst&127)<<16 | src   (src < 65536, dlocal < 128 -> 23 bits)
__global__ __launch_bounds__(256) void scatter_part_kernel(
    const int* __restrict__ src1, const int* __restrict__ dst1,
    const int* __restrict__ src2, const int* __restrict__ dst2,
    const int* __restrict__ H, const int* __restrict__ boffG,
    unsigned* __restrict__ st)
{
  const int bid = blockIdx.x;
  const int v   = bid >= PPART;
  const int p   = v ? bid - PPART : bid;
  const int* __restrict__ src = v ? src2 : src1;
  const int* __restrict__ dst = v ? dst2 : dst1;

  __shared__ int lcur[NBK];
  for (int i = threadIdx.x; i < NBK; i += 256)
    lcur[i] = boffG[v * NBK + i] + H[(v * NBK + i) * PPART + p];
  __syncthreads();
  const int beg = p * CHUNK;
  const int end = (beg + CHUNK < NEDGES) ? beg + CHUNK : NEDGES;
  const int nfull = (end - beg) & ~3;
  for (int j = beg + threadIdx.x * 4; j < beg + nfull; j += 1024) {
    const int4 s4 = *(const int4*)(src + j);
    const int4 d4 = *(const int4*)(dst + j);
    int k;
    k = atomicAdd(&lcur[d4.x >> 7], 1);
    st[k] = ((unsigned)(d4.x & (BW - 1)) << 16) | (unsigned)s4.x;
    k = atomicAdd(&lcur[d4.y >> 7], 1);
    st[k] = ((unsigned)(d4.y & (BW - 1)) << 16) | (unsigned)s4.y;
    k = atomicAdd(&lcur[d4.z >> 7], 1);
    st[k] = ((unsigned)(d4.z & (BW - 1)) << 16) | (unsigned)s4.z;
    k = atomicAdd(&lcur[d4.w >> 7], 1);
    st[k] = ((unsigned)(d4.w & (BW - 1)) << 16) | (unsigned)s4.w;
  }
  for (int j = beg + nfull + threadIdx.x; j < end; j += 256) {
    const int s = src[j], d = dst[j];
    const int k = atomicAdd(&lcur[d >> 7], 1);
    st[k] = ((unsigned)(d & (BW - 1)) << 16) | (unsigned)s;
  }
}

__global__ __launch_bounds__(256) void build_buckets_kernel(
    const unsigned* __restrict__ st, const int* __restrict__ boffG,
    int* __restrict__ rp1, int* __restrict__ rp2,
    int* __restrict__ col1, int* __restrict__ col2)
{
  const int bid = blockIdx.x;
  const int v   = bid >= NBK;
  const int b   = v ? bid - NBK : bid;
  int* __restrict__ rp  = v ? rp2 : rp1;
  int* __restrict__ col = v ? col2 : col1;
  const int tid = threadIdx.x;

  const int off0G  = boffG[bid];
  const int cnt    = boffG[bid + 1] - off0G;
  const int off0   = off0G - v * NEDGES;    // view-local offset
  const int base_d = b * BW;
  const int nd     = (NNODES - base_d < BW) ? (NNODES - base_d) : BW;

  __shared__ int deg[BW];
  __shared__ int loff[BW + 1];
  __shared__ int cur[BW];
  __shared__ int lcol[CAP];

  if (tid < BW) deg[tid] = 0;
  __syncthreads();
  for (int j = tid; j < cnt; j += 256)
    atomicAdd(&deg[st[off0G + j] >> 16], 1);
  __syncthreads();

  if (tid == 0) loff[0] = 0;
  if (tid < BW) loff[tid + 1] = deg[tid];
  __syncthreads();
  for (int off = 1; off < BW; off <<= 1) {
    int t = (tid < BW && tid + 1 >= off) ? loff[tid + 1 - off] : 0;
    __syncthreads();
    if (tid < BW && tid + 1 >= off) loff[tid + 1] += t;
    __syncthreads();
  }
  if (tid < nd) rp[base_d + tid] = off0 + loff[tid];
  if (tid == 0 && b == NBK - 1) rp[NNODES] = NEDGES;
  if (tid < BW) cur[tid] = loff[tid];
  __syncthreads();

  if (cnt <= CAP) {
    for (int j = tid; j < cnt; j += 256) {
      const unsigned pr = st[off0G + j];
      const int k = atomicAdd(&cur[pr >> 16], 1);
      lcol[k] = (int)(pr & 0xFFFFu);
    }
    __syncthreads();
    if (tid < nd) {                   // sort own segment ascending (in LDS)
      const int s0 = loff[tid], s1 = s0 + deg[tid];
      for (int a = s0 + 1; a < s1; ++a) {
        const int key = lcol[a];
        int c = a - 1;
        while (c >= s0 && lcol[c] > key) { lcol[c + 1] = lcol[c]; --c; }
        lcol[c + 1] = key;
      }
    }
    __syncthreads();
    for (int j = tid; j < cnt; j += 256) col[off0 + j] = lcol[j];
  } else {                            // overflow fallback (never for random data)
    for (int j = tid; j < cnt; j += 256) {
      const unsigned pr = st[off0G + j];
      const int k = atomicAdd(&cur[pr >> 16], 1);
      col[off0 + k] = (int)(pr & 0xFFFFu);
    }
    __syncthreads();
    if (tid < nd) {
      const int s0 = off0 + loff[tid], s1 = s0 + deg[tid];
      for (int a = s0 + 1; a < s1; ++a) {
        const int key = col[a];
        int c = a - 1;
        while (c >= s0 && col[c] > key) { col[c + 1] = col[c]; --c; }
        col[c + 1] = key;
      }
    }
  }
}

// ---------------- AGNN layer: fused views, fp16 gathers, DPP reduce ----------
__global__ __launch_bounds__(256) void agnn_layer_kernel(
    const __half* __restrict__ xh, const float* __restrict__ inv,
    const int* __restrict__ rp1, const int* __restrict__ col1,
    const int* __restrict__ rp2, const int* __restrict__ col2,
    const float* __restrict__ beta_p, const float* __restrict__ order_attn,
    __half* __restrict__ yh_out, float* __restrict__ inv_out,
    float* __restrict__ y32_out, int n)
{
  const int wid  = (blockIdx.x * blockDim.x + threadIdx.x) >> 6;
  if (wid >= n) return;
  const int lane = threadIdx.x & 63;
  const int grp  = lane >> 4;        // 0..3  : edge slot within each view
  const int sub  = lane & 15;        // 0..15 : 8 dims each -> 128 dims
  const unsigned subo = (unsigned)sub * 8u;

  const float beta = beta_p[0];
  const float bi   = beta * inv[wid];

  HF8 ud; ud.f = *(const float4*)(xh + ((unsigned)wid * 128u + subo));

  const int beg1 = rp1[wid], end1 = rp1[wid + 1];
  const int beg2 = rp2[wid], end2 = rp2[wid + 1];

  float s1 = 0.f, s2 = 0.f;
  float y1[8], y2[8];
#pragma unroll
  for (int k = 0; k < 8; ++k) { y1[k] = 0.f; y2[k] = 0.f; }

  int j1 = beg1 + grp, j2 = beg2 + grp;
  int c1 = col1[j1];                 // padded: always in-bounds
  int c2 = col2[j2];

  while (j1 < end1 || j2 < end2) {
    const bool p1 = j1 < end1;
    const bool p2 = j2 < end2;

    const float is1 = inv[(unsigned)c1];
    const float is2 = inv[(unsigned)c2];
    HF8 u1; u1.f = *(const float4*)(xh + ((unsigned)c1 * 128u + subo));
    HF8 u2; u2.f = *(const float4*)(xh + ((unsigned)c2 * 128u + subo));

    const int nj1 = j1 + 4, nj2 = j2 + 4;
    c1 = col1[nj1];                  // unconditional prefetch (padded)
    c2 = col2[nj2];

    float d1 = 0.f, d2 = 0.f;
#pragma unroll
    for (int i = 0; i < 4; ++i) {
      d1 = __builtin_amdgcn_fdot2(u1.v[i], ud.v[i], d1, false);
      d2 = __builtin_amdgcn_fdot2(u2.v[i], ud.v[i], d2, false);
    }
    d1 = rowsum16(d1);
    d2 = rowsum16(d2);

    const float w1 = p1 ? __expf(bi * is1 * d1) : 0.f;
    const float w2 = p2 ? __expf(bi * is2 * d2) : 0.f;
    s1 += w1; s2 += w2;
#pragma unroll
    for (int i = 0; i < 4; ++i) {
      y1[2 * i + 0] = fmaf(w1, (float)u1.v[i][0], y1[2 * i + 0]);
      y1[2 * i + 1] = fmaf(w1, (float)u1.v[i][1], y1[2 * i + 1]);
      y2[2 * i + 0] = fmaf(w2, (float)u2.v[i][0], y2[2 * i + 0]);
      y2[2 * i + 1] = fmaf(w2, (float)u2.v[i][1], y2[2 * i + 1]);
    }

    j1 = nj1; j2 = nj2;
  }

  // merge the 4 group-partials (groups differ in lane bits 4..5)
  s1 += __shfl_xor(s1, 16); s1 += __shfl_xor(s1, 32);
  s2 += __shfl_xor(s2, 16); s2 += __shfl_xor(s2, 32);
#pragma unroll
  for (int k = 0; k < 8; ++k) {
    y1[k] += __shfl_xor(y1[k], 16); y1[k] += __shfl_xor(y1[k], 32);
    y2[k] += __shfl_xor(y2[k], 16); y2[k] += __shfl_xor(y2[k], 32);
  }

  const float r1 = (end1 > beg1) ? order_attn[0] / fmaxf(s1, 1e-12f) : 0.f;
  const float r2 = (end2 > beg2) ? order_attn[1] / fmaxf(s2, 1e-12f) : 0.f;
  float acc[8];
#pragma unroll
  for (int k = 0; k < 8; ++k) acc[k] = r1 * y1[k] + r2 * y2[k];

  if (inv_out) {                     // fused row-norm (fp32, pre-rounding)
    float ss = 0.f;
#pragma unroll
    for (int k = 0; k < 8; ++k) ss += acc[k] * acc[k];
    ss = rowsum16(ss);
    if (lane == 0) inv_out[wid] = 1.0f / fmaxf(sqrtf(ss), 1e-12f);
  }

  if (grp == 0) {
    if (yh_out) {
      HF8 o;
      o.h2[0] = __floats2half2_rn(acc[0], acc[1]);
      o.h2[1] = __floats2half2_rn(acc[2], acc[3]);
      o.h2[2] = __floats2half2_rn(acc[4], acc[5]);
      o.h2[3] = __floats2half2_rn(acc[6], acc[7]);
      *(float4*)(yh_out + ((unsigned)wid * 128u + subo)) = o.f;
    }
    if (y32_out) {
      float* yp = y32_out + (size_t)wid * DHID + sub * 8;
      *(float4*)(yp)     = make_float4(acc[0], acc[1], acc[2], acc[3]);
      *(float4*)(yp + 4) = make_float4(acc[4], acc[5], acc[6], acc[7]);
    }
  }
}

// ---------------- launcher ----------------------------------------------------
extern "C" void kernel_launch(void* const* d_in, const int* in_sizes, int n_in,
                              void* d_out, int out_size, void* d_ws, size_t ws_size,
                              hipStream_t stream)
{
  const float* X          = (const float*)d_in[0];
  const int*   src1       = (const int*)d_in[1];
  const int*   dst1       = (const int*)d_in[2];
  const int*   src2       = (const int*)d_in[3];
  const int*   dst2       = (const int*)d_in[4];
  const float* order_attn = (const float*)d_in[5];
  const float* W1         = (const float*)d_in[6];
  const float* b1         = (const float*)d_in[7];
  const float* W2         = (const float*)d_in[8];
  const float* b2         = (const float*)d_in[9];
  const float* beta1      = (const float*)d_in[10];
  const float* beta2      = (const float*)d_in[11];
  float*       out        = (float*)d_out;

  char*  ws  = (char*)d_ws;
  size_t off = 0;
  auto alloc = [&](size_t bytes) -> void* {
    void* p = ws + off;
    off += (bytes + 255) & ~size_t(255);
    return p;
  };
  __half* x1h  = (__half*)alloc((size_t)NNODES * DHID * 2);
  __half* x2h  = (__half*)alloc((size_t)NNODES * DHID * 2);
  __half* x3h  = (__half*)alloc((size_t)NNODES * DHID * 2);
  float*  inv1 = (float*)alloc((size_t)NNODES * 4);
  float*  inv2 = (float*)alloc((size_t)NNODES * 4);
  int*    rp1  = (int*)alloc((size_t)(NNODES + 1) * 4);
  int*    rp2  = (int*)alloc((size_t)(NNODES + 1) * 4);
  int*    col1 = (int*)alloc((size_t)(NEDGES + CPAD) * 4);
  int*    col2 = (int*)alloc((size_t)(NEDGES + CPAD) * 4);
  int*    H    = (int*)alloc((size_t)2 * NBK * PPART * 4);
  int*    btot = (int*)alloc((size_t)2 * NBK * 4);
  int*    boffG= (int*)alloc((size_t)(2 * NBK + 1) * 4);
  unsigned* st = (unsigned*)alloc((size_t)2 * NEDGES * 4);  // packed (dlocal<<16|src)

  const int WB = (NNODES + 3) / 4;   // 4 waves (nodes) per 256-thread block

  hist_part_kernel<<<2 * PPART, 256, 0, stream>>>(dst1, dst2, H);
  scan_bucket_kernel<<<2 * NBK, PPART, 0, stream>>>(H, btot);
  scan_btot_kernel<<<1, 1024, 0, stream>>>(btot, boffG, col1, col2);
  scatter_part_kernel<<<2 * PPART, 256, 0, stream>>>(src1, dst1, src2, dst2,
                                                     H, boffG, st);
  build_buckets_kernel<<<2 * NBK, 256, 0, stream>>>(st, boffG, rp1, rp2, col1, col2);

  fc1_kernel<<<(NNODES + MT - 1) / MT, 256, 0, stream>>>(X, W1, b1, x1h, inv1);

  agnn_layer_kernel<<<WB, 256, 0, stream>>>(x1h, inv1, rp1, col1, rp2, col2,
                                            beta1, order_attn,
                                            x2h, inv2, nullptr, NNODES);
  agnn_layer_kernel<<<WB, 256, 0, stream>>>(x2h, inv2, rp1, col1, rp2, col2,
                                            beta2, order_attn,
                                            x3h, nullptr, nullptr, NNODES);

  fc2_kernel<<<NNODES / 8, 320, 0, stream>>>(x3h, W2, b2, out);
}

// Round 23
// 270.726 us; speedup vs baseline: 1.0479x; 1.0479x over previous
//
#include <hip/hip_runtime.h>
#include <hip/hip_fp16.h>
#include <math.h>

#define NNODES 50000
#define NEDGES 800000
#define DIN    256
#define DHID   128
#define NCLS   40

#define BW    128                    // dst values per bucket
#define NBK   391                    // ceil(NNODES / BW)
#define CAP   6144                   // LDS col capacity per bucket (mean 2048, sd ~45)
#define PPART 256                    // partition blocks per view
#define CHUNK 3128                   // per-block edge span (mult of 4 -> int4 aligned)
#define CPAD  64                     // col array tail padding (zeroed)
#define BK    32                     // fc1 k-tile (16 k-pairs)

typedef _Float16 h2v __attribute__((ext_vector_type(2)));
typedef _Float16 h8v __attribute__((ext_vector_type(8)));
union HF8 { float4 f; __half2 h2[4]; h2v v[4]; };   // 8 fp16 <-> 16 B
union HF4 { float2 f; __half2 h2[2]; };             // 4 fp16 <-> 8 B
union H24 { h8v v; h2v p[4]; };                     // 16 B = 4 k-pairs

// single-cycle cross-lane add via DPP (ctrl must be a compile-time constant)
template <int CTRL>
__device__ __forceinline__ float dpp_add(float d) {
  int t = __builtin_amdgcn_update_dpp(0, __float_as_int(d), CTRL, 0xf, 0xf, true);
  return d + __int_as_float(t);
}
// sum over each 16-lane row; all 16 lanes receive the identical total.
__device__ __forceinline__ float rowsum16(float d) {
  d = dpp_add<0xB1>(d);    // quad_perm [1,0,3,2]  (xor 1)
  d = dpp_add<0x4E>(d);    // quad_perm [2,3,0,1]  (xor 2)
  d = dpp_add<0x141>(d);   // row_half_mirror      (xor 7 pairing of quad sums)
  d = dpp_add<0x128>(d);   // row_ror:8            (xor 8 across 16-row halves)
  return d;
}

// ---------------- fc1: fp16-tile GEMM via v_dot2_f32_f16 ---------------------
// 64 nodes x 128 cols per 256-thread block, thread = 4m x 8n. Tiles staged as
// fp16 (k,k+1) pairs: 48 B LDS per 64 FMAs (0.75 B/FMA, 2x better than fp32
// tiles) and 32 fdot2 instead of 64 v_fma -> halves both the LDS-read pipe
// load (the measured bottleneck) and VALU issue. fp32 accumulation, k-ascending.
__global__ __launch_bounds__(256) void fc1_kernel(
    const float* __restrict__ X, const float* __restrict__ W1,
    const float* __restrict__ b1, __half* __restrict__ x1h,
    float* __restrict__ inv1)
{
  __shared__ h2v As2[BK / 2][68];    // [kp][m] pair (k,k+1) of row m (4.25 KB)
  __shared__ h2v Bs2[BK / 2][132];   // [kp][n] pair (k,k+1) of col n (8.25 KB)
  const int tid   = threadIdx.x;
  const int node0 = blockIdx.x * 64;
  const int tx    = tid & 15;        // n-groups: cols {tx*4..+3} u {64+tx*4..+3}
  const int ty    = tid >> 4;        // m-group: rows ty*4..+3

  float acc[4][8];
#pragma unroll
  for (int i = 0; i < 4; ++i)
#pragma unroll
    for (int j = 0; j < 8; ++j) acc[i][j] = 0.f;

  for (int kt = 0; kt < DIN / BK; ++kt) {
    const int k0 = kt * BK;
    // stage A (X^T, fp16 pairs): 2 float4 per thread
#pragma unroll
    for (int q = 0; q < 2; ++q) {
      const int flat = q * 256 + tid;      // float4 index in 64x(BK/4) grid
      const int row  = flat >> 3;          // 0..63
      const int kk   = (flat & 7) * 4;     // 0..28
      const int mrow = (node0 + row < NNODES) ? node0 + row : NNODES - 1;
      const float4 v = *(const float4*)(X + (size_t)mrow * DIN + k0 + kk);
      h2v p0; p0[0] = (_Float16)v.x; p0[1] = (_Float16)v.y;
      h2v p1; p1[0] = (_Float16)v.z; p1[1] = (_Float16)v.w;
      As2[(kk >> 1) + 0][row] = p0;
      As2[(kk >> 1) + 1][row] = p1;
    }
    // stage B (W1, fp16 pairs): 2 assignments/thread, each 2 float4 loads
#pragma unroll
    for (int q = 0; q < 2; ++q) {
      const int flat = q * 256 + tid;      // 0..511
      const int kp   = flat >> 5;          // 0..15
      const int nq   = (flat & 31) * 4;    // 0..124
      const float4 va = *(const float4*)(W1 + (size_t)(k0 + 2 * kp)     * DHID + nq);
      const float4 vb = *(const float4*)(W1 + (size_t)(k0 + 2 * kp + 1) * DHID + nq);
      h2v t;
      t[0] = (_Float16)va.x; t[1] = (_Float16)vb.x; Bs2[kp][nq + 0] = t;
      t[0] = (_Float16)va.y; t[1] = (_Float16)vb.y; Bs2[kp][nq + 1] = t;
      t[0] = (_Float16)va.z; t[1] = (_Float16)vb.z; Bs2[kp][nq + 2] = t;
      t[0] = (_Float16)va.w; t[1] = (_Float16)vb.w; Bs2[kp][nq + 3] = t;
    }
    __syncthreads();

#pragma unroll 4
    for (int kp = 0; kp < BK / 2; ++kp) {
      H24 a;   a.v   = *(const h8v*)&As2[kp][ty * 4];        // 16 B
      H24 b0;  b0.v  = *(const h8v*)&Bs2[kp][tx * 4];        // 16 B
      H24 b1v; b1v.v = *(const h8v*)&Bs2[kp][64 + tx * 4];   // 16 B
#pragma unroll
      for (int i = 0; i < 4; ++i) {
#pragma unroll
        for (int j = 0; j < 4; ++j) {
          acc[i][j]     = __builtin_amdgcn_fdot2(a.p[i], b0.p[j],  acc[i][j],     false);
          acc[i][4 + j] = __builtin_amdgcn_fdot2(a.p[i], b1v.p[j], acc[i][4 + j], false);
        }
      }
    }
    __syncthreads();
  }

  const float4 bb0 = *(const float4*)(b1 + tx * 4);
  const float4 bb1 = *(const float4*)(b1 + 64 + tx * 4);
  const float bias[8] = {bb0.x, bb0.y, bb0.z, bb0.w, bb1.x, bb1.y, bb1.z, bb1.w};

#pragma unroll
  for (int i = 0; i < 4; ++i) {
    const int row = node0 + ty * 4 + i;
    float v[8];
    float q = 0.f;
#pragma unroll
    for (int j = 0; j < 8; ++j) {
      float t = acc[i][j] + bias[j];
      t = t > 0.f ? t : 0.f;
      v[j] = t;
      q += t * t;
    }
    q = rowsum16(q);                 // reduce over the 16 tx lanes (DPP)
    if (row < NNODES) {
      HF4 o0, o1;
      o0.h2[0] = __floats2half2_rn(v[0], v[1]);
      o0.h2[1] = __floats2half2_rn(v[2], v[3]);
      o1.h2[0] = __floats2half2_rn(v[4], v[5]);
      o1.h2[1] = __floats2half2_rn(v[6], v[7]);
      *(float2*)(x1h + (size_t)row * DHID + tx * 4)      = o0.f;
      *(float2*)(x1h + (size_t)row * DHID + 64 + tx * 4) = o1.f;
      if (tx == 0) inv1[row] = 1.0f / fmaxf(sqrtf(q), 1e-12f);
    }
  }
}

// ---------------- fc2: out = x3h @ W2 + b2, 8 nodes/block (320 thr) ----------
__global__ __launch_bounds__(320) void fc2_kernel(
    const __half* __restrict__ x3h, const float* __restrict__ W2,
    const float* __restrict__ b2, float* __restrict__ out)
{
  __shared__ float Xs[8][DHID];      // 4 KB
  const int tid   = threadIdx.x;
  const int node0 = blockIdx.x * 8;
  if (tid < 128) {                   // 8 rows x 128 halves = 128 x 16B chunks
    HF8 u; u.f = *(const float4*)(x3h + (size_t)node0 * DHID + tid * 8);
    float* dst = &Xs[0][0] + tid * 8;
#pragma unroll
    for (int i = 0; i < 4; ++i) {
      const float2 t = __half22float2(u.h2[i]);
      dst[2 * i] = t.x; dst[2 * i + 1] = t.y;
    }
  }
  __syncthreads();

  const int ns = tid / NCLS;         // 0..7
  const int c  = tid - ns * NCLS;    // 0..39
  float acc = b2[c];
#pragma unroll 8
  for (int k = 0; k < DHID; ++k) acc += Xs[ns][k] * W2[k * NCLS + c];
  out[(size_t)(node0 + ns) * NCLS + c] = acc;
}

// ---------------- CSR build: deterministic two-pass multi-split --------------
__global__ __launch_bounds__(256) void hist_part_kernel(
    const int* __restrict__ dst1, const int* __restrict__ dst2,
    int* __restrict__ H)
{
  const int bid = blockIdx.x;
  const int v   = bid >= PPART;
  const int p   = v ? bid - PPART : bid;
  const int* __restrict__ dst = v ? dst2 : dst1;

  __shared__ int hist[NBK];
  for (int i = threadIdx.x; i < NBK; i += 256) hist[i] = 0;
  __syncthreads();
  const int beg = p * CHUNK;
  const int end = (beg + CHUNK < NEDGES) ? beg + CHUNK : NEDGES;
  const int nfull = (end - beg) & ~3;
  for (int j = beg + threadIdx.x * 4; j < beg + nfull; j += 1024) {
    const int4 d4 = *(const int4*)(dst + j);
    atomicAdd(&hist[d4.x >> 7], 1);
    atomicAdd(&hist[d4.y >> 7], 1);
    atomicAdd(&hist[d4.z >> 7], 1);
    atomicAdd(&hist[d4.w >> 7], 1);
  }
  for (int j = beg + nfull + threadIdx.x; j < end; j += 256)
    atomicAdd(&hist[dst[j] >> 7], 1);
  __syncthreads();
  for (int i = threadIdx.x; i < NBK; i += 256)
    H[(v * NBK + i) * PPART + p] = hist[i];
}

__global__ __launch_bounds__(PPART) void scan_bucket_kernel(
    int* __restrict__ H, int* __restrict__ btot)
{
  const int b   = blockIdx.x;        // 0..2*NBK-1
  const int tid = threadIdx.x;
  __shared__ int sm[PPART];
  const int v = H[b * PPART + tid];
  sm[tid] = v;
  __syncthreads();
  for (int off = 1; off < PPART; off <<= 1) {
    int t = (tid >= off) ? sm[tid - off] : 0;
    __syncthreads();
    sm[tid] += t;
    __syncthreads();
  }
  H[b * PPART + tid] = sm[tid] - v;  // exclusive within bucket
  if (tid == PPART - 1) btot[b] = sm[tid];
}

__global__ __launch_bounds__(1024) void scan_btot_kernel(
    const int* __restrict__ btot, int* __restrict__ boffG,
    int* __restrict__ col1, int* __restrict__ col2)
{
  __shared__ int sm[1024];
  const int tid = threadIdx.x;
  // zero the col tail pads (agnn prefetches read past segment ends)
  if (tid >= 768 && tid < 768 + CPAD) col1[NEDGES + tid - 768] = 0;
  if (tid >= 832 && tid < 832 + CPAD) col2[NEDGES + tid - 832] = 0;
  const int v = (tid < 2 * NBK) ? btot[tid] : 0;
  sm[tid] = v;
  __syncthreads();
  for (int off = 1; off < 1024; off <<= 1) {
    int t = (tid >= off) ? sm[tid - off] : 0;
    __syncthreads();
    sm[tid] += t;
    __syncthreads();
  }
  if (tid < 2 * NBK) boffG[tid] = sm[tid] - v;
  if (tid == 0) boffG[2 * NBK] = 2 * NEDGES;
}

// st element: (dst&127)<<16 | src   (src < 65536, dlocal < 128 -> 23 bits)
__global__ __launch_bounds__(256) void scatter_part_kernel(
    const int* __restrict__ src1, const int* __restrict__ dst1,
    const int* __restrict__ src2, const int* __restrict__ dst2,
    const int* __restrict__ H, const int* __restrict__ boffG,
    unsigned* __restrict__ st)
{
  const int bid = blockIdx.x;
  const int v   = bid >= PPART;
  const int p   = v ? bid - PPART : bid;
  const int* __restrict__ src = v ? src2 : src1;
  const int* __restrict__ dst = v ? dst2 : dst1;

  __shared__ int lcur[NBK];
  for (int i = threadIdx.x; i < NBK; i += 256)
    lcur[i] = boffG[v * NBK + i] + H[(v * NBK + i) * PPART + p];
  __syncthreads();
  const int beg = p * CHUNK;
  const int end = (beg + CHUNK < NEDGES) ? beg + CHUNK : NEDGES;
  const int nfull = (end - beg) & ~3;
  for (int j = beg + threadIdx.x * 4; j < beg + nfull; j += 1024) {
    const int4 s4 = *(const int4*)(src + j);
    const int4 d4 = *(const int4*)(dst + j);
    int k;
    k = atomicAdd(&lcur[d4.x >> 7], 1);
    st[k] = ((unsigned)(d4.x & (BW - 1)) << 16) | (unsigned)s4.x;
    k = atomicAdd(&lcur[d4.y >> 7], 1);
    st[k] = ((unsigned)(d4.y & (BW - 1)) << 16) | (unsigned)s4.y;
    k = atomicAdd(&lcur[d4.z >> 7], 1);
    st[k] = ((unsigned)(d4.z & (BW - 1)) << 16) | (unsigned)s4.z;
    k = atomicAdd(&lcur[d4.w >> 7], 1);
    st[k] = ((unsigned)(d4.w & (BW - 1)) << 16) | (unsigned)s4.w;
  }
  for (int j = beg + nfull + threadIdx.x; j < end; j += 256) {
    const int s = src[j], d = dst[j];
    const int k = atomicAdd(&lcur[d >> 7], 1);
    st[k] = ((unsigned)(d & (BW - 1)) << 16) | (unsigned)s;
  }
}

__global__ __launch_bounds__(256) void build_buckets_kernel(
    const unsigned* __restrict__ st, const int* __restrict__ boffG,
    int* __restrict__ rp1, int* __restrict__ rp2,
    int* __restrict__ col1, int* __restrict__ col2)
{
  const int bid = blockIdx.x;
  const int v   = bid >= NBK;
  const int b   = v ? bid - NBK : bid;
  int* __restrict__ rp  = v ? rp2 : rp1;
  int* __restrict__ col = v ? col2 : col1;
  const int tid = threadIdx.x;

  const int off0G  = boffG[bid];
  const int cnt    = boffG[bid + 1] - off0G;
  const int off0   = off0G - v * NEDGES;    // view-local offset
  const int base_d = b * BW;
  const int nd     = (NNODES - base_d < BW) ? (NNODES - base_d) : BW;

  __shared__ int deg[BW];
  __shared__ int loff[BW + 1];
  __shared__ int cur[BW];
  __shared__ int lcol[CAP];

  if (tid < BW) deg[tid] = 0;
  __syncthreads();
  for (int j = tid; j < cnt; j += 256)
    atomicAdd(&deg[st[off0G + j] >> 16], 1);
  __syncthreads();

  if (tid == 0) loff[0] = 0;
  if (tid < BW) loff[tid + 1] = deg[tid];
  __syncthreads();
  for (int off = 1; off < BW; off <<= 1) {
    int t = (tid < BW && tid + 1 >= off) ? loff[tid + 1 - off] : 0;
    __syncthreads();
    if (tid < BW && tid + 1 >= off) loff[tid + 1] += t;
    __syncthreads();
  }
  if (tid < nd) rp[base_d + tid] = off0 + loff[tid];
  if (tid == 0 && b == NBK - 1) rp[NNODES] = NEDGES;
  if (tid < BW) cur[tid] = loff[tid];
  __syncthreads();

  if (cnt <= CAP) {
    for (int j = tid; j < cnt; j += 256) {
      const unsigned pr = st[off0G + j];
      const int k = atomicAdd(&cur[pr >> 16], 1);
      lcol[k] = (int)(pr & 0xFFFFu);
    }
    __syncthreads();
    if (tid < nd) {                   // sort own segment ascending (in LDS)
      const int s0 = loff[tid], s1 = s0 + deg[tid];
      for (int a = s0 + 1; a < s1; ++a) {
        const int key = lcol[a];
        int c = a - 1;
        while (c >= s0 && lcol[c] > key) { lcol[c + 1] = lcol[c]; --c; }
        lcol[c + 1] = key;
      }
    }
    __syncthreads();
    for (int j = tid; j < cnt; j += 256) col[off0 + j] = lcol[j];
  } else {                            // overflow fallback (never for random data)
    for (int j = tid; j < cnt; j += 256) {
      const unsigned pr = st[off0G + j];
      const int k = atomicAdd(&cur[pr >> 16], 1);
      col[off0 + k] = (int)(pr & 0xFFFFu);
    }
    __syncthreads();
    if (tid < nd) {
      const int s0 = off0 + loff[tid], s1 = s0 + deg[tid];
      for (int a = s0 + 1; a < s1; ++a) {
        const int key = col[a];
        int c = a - 1;
        while (c >= s0 && col[c] > key) { col[c + 1] = col[c]; --c; }
        col[c + 1] = key;
      }
    }
  }
}

// ---------------- AGNN layer: fused views, fp16 gathers, DPP reduce ----------
__global__ __launch_bounds__(256) void agnn_layer_kernel(
    const __half* __restrict__ xh, const float* __restrict__ inv,
    const int* __restrict__ rp1, const int* __restrict__ col1,
    const int* __restrict__ rp2, const int* __restrict__ col2,
    const float* __restrict__ beta_p, const float* __restrict__ order_attn,
    __half* __restrict__ yh_out, float* __restrict__ inv_out,
    float* __restrict__ y32_out, int n)
{
  const int wid  = (blockIdx.x * blockDim.x + threadIdx.x) >> 6;
  if (wid >= n) return;
  const int lane = threadIdx.x & 63;
  const int grp  = lane >> 4;        // 0..3  : edge slot within each view
  const int sub  = lane & 15;        // 0..15 : 8 dims each -> 128 dims
  const unsigned subo = (unsigned)sub * 8u;

  const float beta = beta_p[0];
  const float bi   = beta * inv[wid];

  HF8 ud; ud.f = *(const float4*)(xh + ((unsigned)wid * 128u + subo));

  const int beg1 = rp1[wid], end1 = rp1[wid + 1];
  const int beg2 = rp2[wid], end2 = rp2[wid + 1];

  float s1 = 0.f, s2 = 0.f;
  float y1[8], y2[8];
#pragma unroll
  for (int k = 0; k < 8; ++k) { y1[k] = 0.f; y2[k] = 0.f; }

  int j1 = beg1 + grp, j2 = beg2 + grp;
  int c1 = col1[j1];                 // padded: always in-bounds
  int c2 = col2[j2];

  while (j1 < end1 || j2 < end2) {
    const bool p1 = j1 < end1;
    const bool p2 = j2 < end2;

    const float is1 = inv[(unsigned)c1];
    const float is2 = inv[(unsigned)c2];
    HF8 u1; u1.f = *(const float4*)(xh + ((unsigned)c1 * 128u + subo));
    HF8 u2; u2.f = *(const float4*)(xh + ((unsigned)c2 * 128u + subo));

    const int nj1 = j1 + 4, nj2 = j2 + 4;
    c1 = col1[nj1];                  // unconditional prefetch (padded)
    c2 = col2[nj2];

    float d1 = 0.f, d2 = 0.f;
#pragma unroll
    for (int i = 0; i < 4; ++i) {
      d1 = __builtin_amdgcn_fdot2(u1.v[i], ud.v[i], d1, false);
      d2 = __builtin_amdgcn_fdot2(u2.v[i], ud.v[i], d2, false);
    }
    d1 = rowsum16(d1);
    d2 = rowsum16(d2);

    const float w1 = p1 ? __expf(bi * is1 * d1) : 0.f;
    const float w2 = p2 ? __expf(bi * is2 * d2) : 0.f;
    s1 += w1; s2 += w2;
#pragma unroll
    for (int i = 0; i < 4; ++i) {
      y1[2 * i + 0] = fmaf(w1, (float)u1.v[i][0], y1[2 * i + 0]);
      y1[2 * i + 1] = fmaf(w1, (float)u1.v[i][1], y1[2 * i + 1]);
      y2[2 * i + 0] = fmaf(w2, (float)u2.v[i][0], y2[2 * i + 0]);
      y2[2 * i + 1] = fmaf(w2, (float)u2.v[i][1], y2[2 * i + 1]);
    }

    j1 = nj1; j2 = nj2;
  }

  // merge the 4 group-partials (groups differ in lane bits 4..5)
  s1 += __shfl_xor(s1, 16); s1 += __shfl_xor(s1, 32);
  s2 += __shfl_xor(s2, 16); s2 += __shfl_xor(s2, 32);
#pragma unroll
  for (int k = 0; k < 8; ++k) {
    y1[k] += __shfl_xor(y1[k], 16); y1[k] += __shfl_xor(y1[k], 32);
    y2[k] += __shfl_xor(y2[k], 16); y2[k] += __shfl_xor(y2[k], 32);
  }

  const float r1 = (end1 > beg1) ? order_attn[0] / fmaxf(s1, 1e-12f) : 0.f;
  const float r2 = (end2 > beg2) ? order_attn[1] / fmaxf(s2, 1e-12f) : 0.f;
  float acc[8];
#pragma unroll
  for (int k = 0; k < 8; ++k) acc[k] = r1 * y1[k] + r2 * y2[k];

  if (inv_out) {                     // fused row-norm (fp32, pre-rounding)
    float ss = 0.f;
#pragma unroll
    for (int k = 0; k < 8; ++k) ss += acc[k] * acc[k];
    ss = rowsum16(ss);
    if (lane == 0) inv_out[wid] = 1.0f / fmaxf(sqrtf(ss), 1e-12f);
  }

  if (grp == 0) {
    if (yh_out) {
      HF8 o;
      o.h2[0] = __floats2half2_rn(acc[0], acc[1]);
      o.h2[1] = __floats2half2_rn(acc[2], acc[3]);
      o.h2[2] = __floats2half2_rn(acc[4], acc[5]);
      o.h2[3] = __floats2half2_rn(acc[6], acc[7]);
      *(float4*)(yh_out + ((unsigned)wid * 128u + subo)) = o.f;
    }
    if (y32_out) {
      float* yp = y32_out + (size_t)wid * DHID + sub * 8;
      *(float4*)(yp)     = make_float4(acc[0], acc[1], acc[2], acc[3]);
      *(float4*)(yp + 4) = make_float4(acc[4], acc[5], acc[6], acc[7]);
    }
  }
}

// ---------------- launcher ----------------------------------------------------
extern "C" void kernel_launch(void* const* d_in, const int* in_sizes, int n_in,
                              void* d_out, int out_size, void* d_ws, size_t ws_size,
                              hipStream_t stream)
{
  const float* X          = (const float*)d_in[0];
  const int*   src1       = (const int*)d_in[1];
  const int*   dst1       = (const int*)d_in[2];
  const int*   src2       = (const int*)d_in[3];
  const int*   dst2       = (const int*)d_in[4];
  const float* order_attn = (const float*)d_in[5];
  const float* W1         = (const float*)d_in[6];
  const float* b1         = (const float*)d_in[7];
  const float* W2         = (const float*)d_in[8];
  const float* b2         = (const float*)d_in[9];
  const float* beta1      = (const float*)d_in[10];
  const float* beta2      = (const float*)d_in[11];
  float*       out        = (float*)d_out;

  char*  ws  = (char*)d_ws;
  size_t off = 0;
  auto alloc = [&](size_t bytes) -> void* {
    void* p = ws + off;
    off += (bytes + 255) & ~size_t(255);
    return p;
  };
  __half* x1h  = (__half*)alloc((size_t)NNODES * DHID * 2);
  __half* x2h  = (__half*)alloc((size_t)NNODES * DHID * 2);
  __half* x3h  = (__half*)alloc((size_t)NNODES * DHID * 2);
  float*  inv1 = (float*)alloc((size_t)NNODES * 4);
  float*  inv2 = (float*)alloc((size_t)NNODES * 4);
  int*    rp1  = (int*)alloc((size_t)(NNODES + 1) * 4);
  int*    rp2  = (int*)alloc((size_t)(NNODES + 1) * 4);
  int*    col1 = (int*)alloc((size_t)(NEDGES + CPAD) * 4);
  int*    col2 = (int*)alloc((size_t)(NEDGES + CPAD) * 4);
  int*    H    = (int*)alloc((size_t)2 * NBK * PPART * 4);
  int*    btot = (int*)alloc((size_t)2 * NBK * 4);
  int*    boffG= (int*)alloc((size_t)(2 * NBK + 1) * 4);
  unsigned* st = (unsigned*)alloc((size_t)2 * NEDGES * 4);  // packed (dlocal<<16|src)

  const int WB = (NNODES + 3) / 4;   // 4 waves (nodes) per 256-thread block

  hist_part_kernel<<<2 * PPART, 256, 0, stream>>>(dst1, dst2, H);
  scan_bucket_kernel<<<2 * NBK, PPART, 0, stream>>>(H, btot);
  scan_btot_kernel<<<1, 1024, 0, stream>>>(btot, boffG, col1, col2);
  scatter_part_kernel<<<2 * PPART, 256, 0, stream>>>(src1, dst1, src2, dst2,
                                                     H, boffG, st);
  build_buckets_kernel<<<2 * NBK, 256, 0, stream>>>(st, boffG, rp1, rp2, col1, col2);

  fc1_kernel<<<(NNODES + 63) / 64, 256, 0, stream>>>(X, W1, b1, x1h, inv1);

  agnn_layer_kernel<<<WB, 256, 0, stream>>>(x1h, inv1, rp1, col1, rp2, col2,
                                            beta1, order_attn,
                                            x2h, inv2, nullptr, NNODES);
  agnn_layer_kernel<<<WB, 256, 0, stream>>>(x2h, inv2, rp1, col1, rp2, col2,
                                            beta2, order_attn,
                                            x3h, nullptr, nullptr, NNODES);

  fc2_kernel<<<NNODES / 8, 320, 0, stream>>>(x3h, W2, b2, out);
}

// Round 24
// 270.245 us; speedup vs baseline: 1.0498x; 1.0018x over previous
//
#include <hip/hip_runtime.h>
#include <hip/hip_fp16.h>
#include <math.h>

#define NNODES 50000
#define NEDGES 800000
#define DIN    256
#define DHID   128
#define NCLS   40

#define BW    128                    // dst values per bucket
#define NBK   391                    // ceil(NNODES / BW)
#define CAP   6144                   // LDS col capacity per bucket (mean 2048, sd ~45)
#define PPART 256                    // partition blocks per view
#define CHUNK 3128                   // per-block edge span (mult of 4 -> int4 aligned)
#define CPAD  64                     // col array tail padding (zeroed)
#define BK    32                     // fc1 k-tile (16 k-pairs)

typedef _Float16 h2v __attribute__((ext_vector_type(2)));
typedef _Float16 h8v __attribute__((ext_vector_type(8)));
union HF8 { float4 f; __half2 h2[4]; h2v v[4]; };   // 8 fp16 <-> 16 B
union HF4 { float2 f; __half2 h2[2]; };             // 4 fp16 <-> 8 B
union H24 { h8v v; h2v p[4]; };                     // 16 B = 4 k-pairs

// single-cycle cross-lane add via DPP (ctrl must be a compile-time constant)
template <int CTRL>
__device__ __forceinline__ float dpp_add(float d) {
  int t = __builtin_amdgcn_update_dpp(0, __float_as_int(d), CTRL, 0xf, 0xf, true);
  return d + __int_as_float(t);
}
// sum over each 16-lane row; all 16 lanes receive the identical total.
__device__ __forceinline__ float rowsum16(float d) {
  d = dpp_add<0xB1>(d);    // quad_perm [1,0,3,2]  (xor 1)
  d = dpp_add<0x4E>(d);    // quad_perm [2,3,0,1]  (xor 2)
  d = dpp_add<0x141>(d);   // row_half_mirror      (xor 7 pairing of quad sums)
  d = dpp_add<0x128>(d);   // row_ror:8            (xor 8 across 16-row halves)
  return d;
}

// ---------------- fc1: fp16-tile GEMM via v_dot2_f32_f16, reg-dbuf staging ---
// 64 nodes x 128 cols per 256-thread block, thread = 4m x 8n. Tiles staged as
// fp16 (k,k+1) pairs. Register double-buffer: tile kt+1's global loads issue
// right after the first barrier and land during tile kt's ~1024-cycle fdot2
// block (grid is only ~3 blocks/CU, so TLP alone can't hide the ~600-cycle
// staging latency -- measured VALUBusy 39%). Bit-exact: same loads, same
// converts, same k-ascending accumulation order.
__global__ __launch_bounds__(256) void fc1_kernel(
    const float* __restrict__ X, const float* __restrict__ W1,
    const float* __restrict__ b1, __half* __restrict__ x1h,
    float* __restrict__ inv1)
{
  __shared__ h2v As2[BK / 2][68];    // [kp][m] pair (k,k+1) of row m (4.25 KB)
  __shared__ h2v Bs2[BK / 2][132];   // [kp][n] pair (k,k+1) of col n (8.25 KB)
  const int tid   = threadIdx.x;
  const int node0 = blockIdx.x * 64;
  const int tx    = tid & 15;        // n-groups: cols {tx*4..+3} u {64+tx*4..+3}
  const int ty    = tid >> 4;        // m-group: rows ty*4..+3

  // per-thread staging addresses (fixed across tiles except k0)
  const int arow  = tid >> 3;              // 0..31 used twice (q*256)/8 pattern
  float4 ra[2];                            // A stage regs
  float4 rb[2][2];                         // B stage regs

  auto load_tile = [&](int kt) {
    const int k0 = kt * BK;
#pragma unroll
    for (int q = 0; q < 2; ++q) {
      const int flat = q * 256 + tid;      // float4 index in 64x(BK/4) grid
      const int row  = flat >> 3;          // 0..63
      const int kk   = (flat & 7) * 4;     // 0..28
      const int mrow = (node0 + row < NNODES) ? node0 + row : NNODES - 1;
      ra[q] = *(const float4*)(X + (size_t)mrow * DIN + k0 + kk);
    }
#pragma unroll
    for (int q = 0; q < 2; ++q) {
      const int flat = q * 256 + tid;      // 0..511
      const int kp   = flat >> 5;          // 0..15
      const int nq   = (flat & 31) * 4;    // 0..124
      rb[q][0] = *(const float4*)(W1 + (size_t)(k0 + 2 * kp)     * DHID + nq);
      rb[q][1] = *(const float4*)(W1 + (size_t)(k0 + 2 * kp + 1) * DHID + nq);
    }
  };
  auto store_tile = [&]() {
#pragma unroll
    for (int q = 0; q < 2; ++q) {
      const int flat = q * 256 + tid;
      const int row  = flat >> 3;
      const int kk   = (flat & 7) * 4;
      const float4 v = ra[q];
      h2v p0; p0[0] = (_Float16)v.x; p0[1] = (_Float16)v.y;
      h2v p1; p1[0] = (_Float16)v.z; p1[1] = (_Float16)v.w;
      As2[(kk >> 1) + 0][row] = p0;
      As2[(kk >> 1) + 1][row] = p1;
    }
#pragma unroll
    for (int q = 0; q < 2; ++q) {
      const int flat = q * 256 + tid;
      const int kp   = flat >> 5;
      const int nq   = (flat & 31) * 4;
      const float4 va = rb[q][0], vb = rb[q][1];
      h2v t;
      t[0] = (_Float16)va.x; t[1] = (_Float16)vb.x; Bs2[kp][nq + 0] = t;
      t[0] = (_Float16)va.y; t[1] = (_Float16)vb.y; Bs2[kp][nq + 1] = t;
      t[0] = (_Float16)va.z; t[1] = (_Float16)vb.z; Bs2[kp][nq + 2] = t;
      t[0] = (_Float16)va.w; t[1] = (_Float16)vb.w; Bs2[kp][nq + 3] = t;
    }
  };
  (void)arow;

  float acc[4][8];
#pragma unroll
  for (int i = 0; i < 4; ++i)
#pragma unroll
    for (int j = 0; j < 8; ++j) acc[i][j] = 0.f;

  load_tile(0);
  for (int kt = 0; kt < DIN / BK; ++kt) {
    store_tile();
    __syncthreads();
    if (kt + 1 < DIN / BK) load_tile(kt + 1);   // in flight during compute

#pragma unroll 4
    for (int kp = 0; kp < BK / 2; ++kp) {
      H24 a;   a.v   = *(const h8v*)&As2[kp][ty * 4];        // 16 B
      H24 b0;  b0.v  = *(const h8v*)&Bs2[kp][tx * 4];        // 16 B
      H24 b1v; b1v.v = *(const h8v*)&Bs2[kp][64 + tx * 4];   // 16 B
#pragma unroll
      for (int i = 0; i < 4; ++i) {
#pragma unroll
        for (int j = 0; j < 4; ++j) {
          acc[i][j]     = __builtin_amdgcn_fdot2(a.p[i], b0.p[j],  acc[i][j],     false);
          acc[i][4 + j] = __builtin_amdgcn_fdot2(a.p[i], b1v.p[j], acc[i][4 + j], false);
        }
      }
    }
    __syncthreads();
  }

  const float4 bb0 = *(const float4*)(b1 + tx * 4);
  const float4 bb1 = *(const float4*)(b1 + 64 + tx * 4);
  const float bias[8] = {bb0.x, bb0.y, bb0.z, bb0.w, bb1.x, bb1.y, bb1.z, bb1.w};

#pragma unroll
  for (int i = 0; i < 4; ++i) {
    const int row = node0 + ty * 4 + i;
    float v[8];
    float q = 0.f;
#pragma unroll
    for (int j = 0; j < 8; ++j) {
      float t = acc[i][j] + bias[j];
      t = t > 0.f ? t : 0.f;
      v[j] = t;
      q += t * t;
    }
    q = rowsum16(q);                 // reduce over the 16 tx lanes (DPP)
    if (row < NNODES) {
      HF4 o0, o1;
      o0.h2[0] = __floats2half2_rn(v[0], v[1]);
      o0.h2[1] = __floats2half2_rn(v[2], v[3]);
      o1.h2[0] = __floats2half2_rn(v[4], v[5]);
      o1.h2[1] = __floats2half2_rn(v[6], v[7]);
      *(float2*)(x1h + (size_t)row * DHID + tx * 4)      = o0.f;
      *(float2*)(x1h + (size_t)row * DHID + 64 + tx * 4) = o1.f;
      if (tx == 0) inv1[row] = 1.0f / fmaxf(sqrtf(q), 1e-12f);
    }
  }
}

// ---------------- fc2: out = x3h @ W2 + b2, 8 nodes/block (320 thr) ----------
__global__ __launch_bounds__(320) void fc2_kernel(
    const __half* __restrict__ x3h, const float* __restrict__ W2,
    const float* __restrict__ b2, float* __restrict__ out)
{
  __shared__ float Xs[8][DHID];      // 4 KB
  const int tid   = threadIdx.x;
  const int node0 = blockIdx.x * 8;
  if (tid < 128) {                   // 8 rows x 128 halves = 128 x 16B chunks
    HF8 u; u.f = *(const float4*)(x3h + (size_t)node0 * DHID + tid * 8);
    float* dst = &Xs[0][0] + tid * 8;
#pragma unroll
    for (int i = 0; i < 4; ++i) {
      const float2 t = __half22float2(u.h2[i]);
      dst[2 * i] = t.x; dst[2 * i + 1] = t.y;
    }
  }
  __syncthreads();

  const int ns = tid / NCLS;         // 0..7
  const int c  = tid - ns * NCLS;    // 0..39
  float acc = b2[c];
#pragma unroll 8
  for (int k = 0; k < DHID; ++k) acc += Xs[ns][k] * W2[k * NCLS + c];
  out[(size_t)(node0 + ns) * NCLS + c] = acc;
}

// ---------------- CSR build: deterministic two-pass multi-split --------------
__global__ __launch_bounds__(256) void hist_part_kernel(
    const int* __restrict__ dst1, const int* __restrict__ dst2,
    int* __restrict__ H)
{
  const int bid = blockIdx.x;
  const int v   = bid >= PPART;
  const int p   = v ? bid - PPART : bid;
  const int* __restrict__ dst = v ? dst2 : dst1;

  __shared__ int hist[NBK];
  for (int i = threadIdx.x; i < NBK; i += 256) hist[i] = 0;
  __syncthreads();
  const int beg = p * CHUNK;
  const int end = (beg + CHUNK < NEDGES) ? beg + CHUNK : NEDGES;
  const int nfull = (end - beg) & ~3;
  for (int j = beg + threadIdx.x * 4; j < beg + nfull; j += 1024) {
    const int4 d4 = *(const int4*)(dst + j);
    atomicAdd(&hist[d4.x >> 7], 1);
    atomicAdd(&hist[d4.y >> 7], 1);
    atomicAdd(&hist[d4.z >> 7], 1);
    atomicAdd(&hist[d4.w >> 7], 1);
  }
  for (int j = beg + nfull + threadIdx.x; j < end; j += 256)
    atomicAdd(&hist[dst[j] >> 7], 1);
  __syncthreads();
  for (int i = threadIdx.x; i < NBK; i += 256)
    H[(v * NBK + i) * PPART + p] = hist[i];
}

__global__ __launch_bounds__(PPART) void scan_bucket_kernel(
    int* __restrict__ H, int* __restrict__ btot)
{
  const int b   = blockIdx.x;        // 0..2*NBK-1
  const int tid = threadIdx.x;
  __shared__ int sm[PPART];
  const int v = H[b * PPART + tid];
  sm[tid] = v;
  __syncthreads();
  for (int off = 1; off < PPART; off <<= 1) {
    int t = (tid >= off) ? sm[tid - off] : 0;
    __syncthreads();
    sm[tid] += t;
    __syncthreads();
  }
  H[b * PPART + tid] = sm[tid] - v;  // exclusive within bucket
  if (tid == PPART - 1) btot[b] = sm[tid];
}

__global__ __launch_bounds__(1024) void scan_btot_kernel(
    const int* __restrict__ btot, int* __restrict__ boffG,
    int* __restrict__ col1, int* __restrict__ col2)
{
  __shared__ int sm[1024];
  const int tid = threadIdx.x;
  // zero the col tail pads (agnn prefetches read past segment ends)
  if (tid >= 768 && tid < 768 + CPAD) col1[NEDGES + tid - 768] = 0;
  if (tid >= 832 && tid < 832 + CPAD) col2[NEDGES + tid - 832] = 0;
  const int v = (tid < 2 * NBK) ? btot[tid] : 0;
  sm[tid] = v;
  __syncthreads();
  for (int off = 1; off < 1024; off <<= 1) {
    int t = (tid >= off) ? sm[tid - off] : 0;
    __syncthreads();
    sm[tid] += t;
    __syncthreads();
  }
  if (tid < 2 * NBK) boffG[tid] = sm[tid] - v;
  if (tid == 0) boffG[2 * NBK] = 2 * NEDGES;
}

// st element: (dst&127)<<16 | src   (src < 65536, dlocal < 128 -> 23 bits)
__global__ __launch_bounds__(256) void scatter_part_kernel(
    const int* __restrict__ src1, const int* __restrict__ dst1,
    const int* __restrict__ src2, const int* __restrict__ dst2,
    const int* __restrict__ H, const int* __restrict__ boffG,
    unsigned* __restrict__ st)
{
  const int bid = blockIdx.x;
  const int v   = bid >= PPART;
  const int p   = v ? bid - PPART : bid;
  const int* __restrict__ src = v ? src2 : src1;
  const int* __restrict__ dst = v ? dst2 : dst1;

  __shared__ int lcur[NBK];
  for (int i = threadIdx.x; i < NBK; i += 256)
    lcur[i] = boffG[v * NBK + i] + H[(v * NBK + i) * PPART + p];
  __syncthreads();
  const int beg = p * CHUNK;
  const int end = (beg + CHUNK < NEDGES) ? beg + CHUNK : NEDGES;
  const int nfull = (end - beg) & ~3;
  for (int j = beg + threadIdx.x * 4; j < beg + nfull; j += 1024) {
    const int4 s4 = *(const int4*)(src + j);
    const int4 d4 = *(const int4*)(dst + j);
    int k;
    k = atomicAdd(&lcur[d4.x >> 7], 1);
    st[k] = ((unsigned)(d4.x & (BW - 1)) << 16) | (unsigned)s4.x;
    k = atomicAdd(&lcur[d4.y >> 7], 1);
    st[k] = ((unsigned)(d4.y & (BW - 1)) << 16) | (unsigned)s4.y;
    k = atomicAdd(&lcur[d4.z >> 7], 1);
    st[k] = ((unsigned)(d4.z & (BW - 1)) << 16) | (unsigned)s4.z;
    k = atomicAdd(&lcur[d4.w >> 7], 1);
    st[k] = ((unsigned)(d4.w & (BW - 1)) << 16) | (unsigned)s4.w;
  }
  for (int j = beg + nfull + threadIdx.x; j < end; j += 256) {
    const int s = src[j], d = dst[j];
    const int k = atomicAdd(&lcur[d >> 7], 1);
    st[k] = ((unsigned)(d & (BW - 1)) << 16) | (unsigned)s;
  }
}

__global__ __launch_bounds__(256) void build_buckets_kernel(
    const unsigned* __restrict__ st, const int* __restrict__ boffG,
    int* __restrict__ rp1, int* __restrict__ rp2,
    int* __restrict__ col1, int* __restrict__ col2)
{
  const int bid = blockIdx.x;
  const int v   = bid >= NBK;
  const int b   = v ? bid - NBK : bid;
  int* __restrict__ rp  = v ? rp2 : rp1;
  int* __restrict__ col = v ? col2 : col1;
  const int tid = threadIdx.x;

  const int off0G  = boffG[bid];
  const int cnt    = boffG[bid + 1] - off0G;
  const int off0   = off0G - v * NEDGES;    // view-local offset
  const int base_d = b * BW;
  const int nd     = (NNODES - base_d < BW) ? (NNODES - base_d) : BW;

  __shared__ int deg[BW];
  __shared__ int loff[BW + 1];
  __shared__ int cur[BW];
  __shared__ int lcol[CAP];

  if (tid < BW) deg[tid] = 0;
  __syncthreads();
  for (int j = tid; j < cnt; j += 256)
    atomicAdd(&deg[st[off0G + j] >> 16], 1);
  __syncthreads();

  if (tid == 0) loff[0] = 0;
  if (tid < BW) loff[tid + 1] = deg[tid];
  __syncthreads();
  for (int off = 1; off < BW; off <<= 1) {
    int t = (tid < BW && tid + 1 >= off) ? loff[tid + 1 - off] : 0;
    __syncthreads();
    if (tid < BW && tid + 1 >= off) loff[tid + 1] += t;
    __syncthreads();
  }
  if (tid < nd) rp[base_d + tid] = off0 + loff[tid];
  if (tid == 0 && b == NBK - 1) rp[NNODES] = NEDGES;
  if (tid < BW) cur[tid] = loff[tid];
  __syncthreads();

  if (cnt <= CAP) {
    for (int j = tid; j < cnt; j += 256) {
      const unsigned pr = st[off0G + j];
      const int k = atomicAdd(&cur[pr >> 16], 1);
      lcol[k] = (int)(pr & 0xFFFFu);
    }
    __syncthreads();
    if (tid < nd) {                   // sort own segment ascending (in LDS)
      const int s0 = loff[tid], s1 = s0 + deg[tid];
      for (int a = s0 + 1; a < s1; ++a) {
        const int key = lcol[a];
        int c = a - 1;
        while (c >= s0 && lcol[c] > key) { lcol[c + 1] = lcol[c]; --c; }
        lcol[c + 1] = key;
      }
    }
    __syncthreads();
    for (int j = tid; j < cnt; j += 256) col[off0 + j] = lcol[j];
  } else {                            // overflow fallback (never for random data)
    for (int j = tid; j < cnt; j += 256) {
      const unsigned pr = st[off0G + j];
      const int k = atomicAdd(&cur[pr >> 16], 1);
      col[off0 + k] = (int)(pr & 0xFFFFu);
    }
    __syncthreads();
    if (tid < nd) {
      const int s0 = off0 + loff[tid], s1 = s0 + deg[tid];
      for (int a = s0 + 1; a < s1; ++a) {
        const int key = col[a];
        int c = a - 1;
        while (c >= s0 && col[c] > key) { col[c + 1] = col[c]; --c; }
        col[c + 1] = key;
      }
    }
  }
}

// ---------------- AGNN layer: fused views, fp16 gathers, DPP reduce ----------
__global__ __launch_bounds__(256) void agnn_layer_kernel(
    const __half* __restrict__ xh, const float* __restrict__ inv,
    const int* __restrict__ rp1, const int* __restrict__ col1,
    const int* __restrict__ rp2, const int* __restrict__ col2,
    const float* __restrict__ beta_p, const float* __restrict__ order_attn,
    __half* __restrict__ yh_out, float* __restrict__ inv_out,
    float* __restrict__ y32_out, int n)
{
  const int wid  = (blockIdx.x * blockDim.x + threadIdx.x) >> 6;
  if (wid >= n) return;
  const int lane = threadIdx.x & 63;
  const int grp  = lane >> 4;        // 0..3  : edge slot within each view
  const int sub  = lane & 15;        // 0..15 : 8 dims each -> 128 dims
  const unsigned subo = (unsigned)sub * 8u;

  const float beta = beta_p[0];
  const float bi   = beta * inv[wid];

  HF8 ud; ud.f = *(const float4*)(xh + ((unsigned)wid * 128u + subo));

  const int beg1 = rp1[wid], end1 = rp1[wid + 1];
  const int beg2 = rp2[wid], end2 = rp2[wid + 1];

  float s1 = 0.f, s2 = 0.f;
  float y1[8], y2[8];
#pragma unroll
  for (int k = 0; k < 8; ++k) { y1[k] = 0.f; y2[k] = 0.f; }

  int j1 = beg1 + grp, j2 = beg2 + grp;
  int c1 = col1[j1];                 // padded: always in-bounds
  int c2 = col2[j2];

  while (j1 < end1 || j2 < end2) {
    const bool p1 = j1 < end1;
    const bool p2 = j2 < end2;

    const float is1 = inv[(unsigned)c1];
    const float is2 = inv[(unsigned)c2];
    HF8 u1; u1.f = *(const float4*)(xh + ((unsigned)c1 * 128u + subo));
    HF8 u2; u2.f = *(const float4*)(xh + ((unsigned)c2 * 128u + subo));

    const int nj1 = j1 + 4, nj2 = j2 + 4;
    c1 = col1[nj1];                  // unconditional prefetch (padded)
    c2 = col2[nj2];

    float d1 = 0.f, d2 = 0.f;
#pragma unroll
    for (int i = 0; i < 4; ++i) {
      d1 = __builtin_amdgcn_fdot2(u1.v[i], ud.v[i], d1, false);
      d2 = __builtin_amdgcn_fdot2(u2.v[i], ud.v[i], d2, false);
    }
    d1 = rowsum16(d1);
    d2 = rowsum16(d2);

    const float w1 = p1 ? __expf(bi * is1 * d1) : 0.f;
    const float w2 = p2 ? __expf(bi * is2 * d2) : 0.f;
    s1 += w1; s2 += w2;
#pragma unroll
    for (int i = 0; i < 4; ++i) {
      y1[2 * i + 0] = fmaf(w1, (float)u1.v[i][0], y1[2 * i + 0]);
      y1[2 * i + 1] = fmaf(w1, (float)u1.v[i][1], y1[2 * i + 1]);
      y2[2 * i + 0] = fmaf(w2, (float)u2.v[i][0], y2[2 * i + 0]);
      y2[2 * i + 1] = fmaf(w2, (float)u2.v[i][1], y2[2 * i + 1]);
    }

    j1 = nj1; j2 = nj2;
  }

  // merge the 4 group-partials (groups differ in lane bits 4..5)
  s1 += __shfl_xor(s1, 16); s1 += __shfl_xor(s1, 32);
  s2 += __shfl_xor(s2, 16); s2 += __shfl_xor(s2, 32);
#pragma unroll
  for (int k = 0; k < 8; ++k) {
    y1[k] += __shfl_xor(y1[k], 16); y1[k] += __shfl_xor(y1[k], 32);
    y2[k] += __shfl_xor(y2[k], 16); y2[k] += __shfl_xor(y2[k], 32);
  }

  const float r1 = (end1 > beg1) ? order_attn[0] / fmaxf(s1, 1e-12f) : 0.f;
  const float r2 = (end2 > beg2) ? order_attn[1] / fmaxf(s2, 1e-12f) : 0.f;
  float acc[8];
#pragma unroll
  for (int k = 0; k < 8; ++k) acc[k] = r1 * y1[k] + r2 * y2[k];

  if (inv_out) {                     // fused row-norm (fp32, pre-rounding)
    float ss = 0.f;
#pragma unroll
    for (int k = 0; k < 8; ++k) ss += acc[k] * acc[k];
    ss = rowsum16(ss);
    if (lane == 0) inv_out[wid] = 1.0f / fmaxf(sqrtf(ss), 1e-12f);
  }

  if (grp == 0) {
    if (yh_out) {
      HF8 o;
      o.h2[0] = __floats2half2_rn(acc[0], acc[1]);
      o.h2[1] = __floats2half2_rn(acc[2], acc[3]);
      o.h2[2] = __floats2half2_rn(acc[4], acc[5]);
      o.h2[3] = __floats2half2_rn(acc[6], acc[7]);
      *(float4*)(yh_out + ((unsigned)wid * 128u + subo)) = o.f;
    }
    if (y32_out) {
      float* yp = y32_out + (size_t)wid * DHID + sub * 8;
      *(float4*)(yp)     = make_float4(acc[0], acc[1], acc[2], acc[3]);
      *(float4*)(yp + 4) = make_float4(acc[4], acc[5], acc[6], acc[7]);
    }
  }
}

// ---------------- launcher ----------------------------------------------------
extern "C" void kernel_launch(void* const* d_in, const int* in_sizes, int n_in,
                              void* d_out, int out_size, void* d_ws, size_t ws_size,
                              hipStream_t stream)
{
  const float* X          = (const float*)d_in[0];
  const int*   src1       = (const int*)d_in[1];
  const int*   dst1       = (const int*)d_in[2];
  const int*   src2       = (const int*)d_in[3];
  const int*   dst2       = (const int*)d_in[4];
  const float* order_attn = (const float*)d_in[5];
  const float* W1         = (const float*)d_in[6];
  const float* b1         = (const float*)d_in[7];
  const float* W2         = (const float*)d_in[8];
  const float* b2         = (const float*)d_in[9];
  const float* beta1      = (const float*)d_in[10];
  const float* beta2      = (const float*)d_in[11];
  float*       out        = (float*)d_out;

  char*  ws  = (char*)d_ws;
  size_t off = 0;
  auto alloc = [&](size_t bytes) -> void* {
    void* p = ws + off;
    off += (bytes + 255) & ~size_t(255);
    return p;
  };
  __half* x1h  = (__half*)alloc((size_t)NNODES * DHID * 2);
  __half* x2h  = (__half*)alloc((size_t)NNODES * DHID * 2);
  __half* x3h  = (__half*)alloc((size_t)NNODES * DHID * 2);
  float*  inv1 = (float*)alloc((size_t)NNODES * 4);
  float*  inv2 = (float*)alloc((size_t)NNODES * 4);
  int*    rp1  = (int*)alloc((size_t)(NNODES + 1) * 4);
  int*    rp2  = (int*)alloc((size_t)(NNODES + 1) * 4);
  int*    col1 = (int*)alloc((size_t)(NEDGES + CPAD) * 4);
  int*    col2 = (int*)alloc((size_t)(NEDGES + CPAD) * 4);
  int*    H    = (int*)alloc((size_t)2 * NBK * PPART * 4);
  int*    btot = (int*)alloc((size_t)2 * NBK * 4);
  int*    boffG= (int*)alloc((size_t)(2 * NBK + 1) * 4);
  unsigned* st = (unsigned*)alloc((size_t)2 * NEDGES * 4);  // packed (dlocal<<16|src)

  const int WB = (NNODES + 3) / 4;   // 4 waves (nodes) per 256-thread block

  hist_part_kernel<<<2 * PPART, 256, 0, stream>>>(dst1, dst2, H);
  scan_bucket_kernel<<<2 * NBK, PPART, 0, stream>>>(H, btot);
  scan_btot_kernel<<<1, 1024, 0, stream>>>(btot, boffG, col1, col2);
  scatter_part_kernel<<<2 * PPART, 256, 0, stream>>>(src1, dst1, src2, dst2,
                                                     H, boffG, st);
  build_buckets_kernel<<<2 * NBK, 256, 0, stream>>>(st, boffG, rp1, rp2, col1, col2);

  fc1_kernel<<<(NNODES + 63) / 64, 256, 0, stream>>>(X, W1, b1, x1h, inv1);

  agnn_layer_kernel<<<WB, 256, 0, stream>>>(x1h, inv1, rp1, col1, rp2, col2,
                                            beta1, order_attn,
                                            x2h, inv2, nullptr, NNODES);
  agnn_layer_kernel<<<WB, 256, 0, stream>>>(x2h, inv2, rp1, col1, rp2, col2,
                                            beta2, order_attn,
                                            x3h, nullptr, nullptr, NNODES);

  fc2_kernel<<<NNODES / 8, 320, 0, stream>>>(x3h, W2, b2, out);
}